// Round 5
// baseline (406.445 us; speedup 1.0000x reference)
//
#include <hip/hip_runtime.h>
#include <math.h>

// Problem constants
#define TT 9000          // samples per channel
#define DT 300           // crop length
#define KK 64            // crops per channel
#define NB 35            // band bins: rfft bins 7..41
#define KMIN 7
#define NCH 4096         // B*C channels
#define NPAIR (KK * NB)  // 2240 outputs per channel

// GEMM per channel: C[64 x 96] = A[64 x 320] * W[320 x 96]  (16x16x32 bf16 MFMA)
// v6: persistent producer/consumer block. Cycle accounting of v5 (~79us) shows
// LDS-pipe bound: random-row A-reads from shared sig are ~4-way bank-conflicted
// AND re-read 3x (once per pg wave) -> ~11k LDS cycles/channel/CU ~= 74us total.
// Fix: pre-gather crops into conflict-free rows cb[64][328] (bank =
// 4*((c+quad)&8-group), structural minimum; gather conflicts paid once with
// coalesced writes), and hide the gather under compute with dedicated waves:
//  - 512 blocks x 1024 threads (16 waves), each block owns 8 channels
//  - LDS: W 60 KB (staged once, global_load_lds) + cb[2] 2x42 KB (double
//    buffer) + part = 143 KB -> 1 block/CU, 16 waves
//  - per channel: waves 0-11 (4 M-tiles x 3 pg) k-loop = 3x ds_read_b128
//    (A, Wcos, Wsin; all conflict-free) + 2 MFMA per ks; waves 12-15 gather
//    the NEXT channel's crops from L2/L3 into cb[next]
// New floor: ~4.3k LDS cy/channel/CU ~= 30us aggregate.

typedef __bf16 bf16;
typedef __attribute__((ext_vector_type(8))) __bf16 bf16x8;
typedef __attribute__((ext_vector_type(4))) __bf16 bf16x4;
typedef __attribute__((ext_vector_type(4))) float f32x4;

#define NFRAG_ELEMS (10 * 6 * 64 * 8)   // 30720 bf16 = 61440 B in d_ws
#define WBYTES 61440

// W table in B-fragment order: flat idx ((kstep*6 + nt)*64 + lane)*8 + j
// B-frag layout (16x16x32): lane l holds B[k = kstep*32 + (l>>4)*8 + j][n = l&15]
__global__ void build_w(bf16* __restrict__ tab) {
    int i = blockIdx.x * blockDim.x + threadIdx.x;
    if (i >= NFRAG_ELEMS) return;
    int j    = i & 7;
    int l    = (i >> 3) & 63;
    int f    = i >> 9;           // frag index = kstep*6 + nt
    int nt   = f % 6;
    int ks   = f / 6;
    int quad = l >> 4;
    int c    = l & 15;
    int k    = ks * 32 + quad * 8 + j;   // time index 0..319
    int jf   = (nt % 3) * 16 + c;        // band bin index 0..47
    float v = 0.0f;
    if (jf <= NB - 1 && k < DT) {
        int bin = jf + KMIN;                       // rfft bin 7..41
        int ph  = (bin * k) % DT;                  // exact integer phase
        float ang = 0.02094395102393195f * (float)ph;  // 2*pi/300 * ph
        v = (nt >= 3) ? sinf(ang) : cosf(ang);
    }
    tab[i] = (bf16)v;
}

#define ROWB 656            // bytes per crop row: 328 bf16 (320 data + 16B pad)
#define CBB  (KK * ROWB)    // 41984 B per crop buffer
#define CPB  8              // channels per block
#define NBLK (NCH / CPB)    // 512 blocks

// Gather one channel's 64 crops into cb rows (bf16). 5120 chunks of 4 samples.
// Chunks p>=75 are the zero pad (k 300..319: W rows are zero, but poison*0
// must not make NaN). Global reads are 4 scalar dwords (offsets give only
// 4B alignment); consecutive threads walk consecutive chunks -> coalesced
// runs of 1.2 KB per crop, served from L2/L3 (channel fits easily).
__device__ __forceinline__ void gather_ch(const float* __restrict__ chan,
                                          const int* __restrict__ offp,
                                          unsigned char* __restrict__ dst,
                                          int t, int nthreads, int niter) {
#pragma unroll
    for (int i = 0; i < niter; ++i) {
        int n = t + i * nthreads;        // niter*nthreads == 5120 exactly
        int r = n / 80;                  // crop (magic-mul)
        int p = n - r * 80;              // 4-sample chunk within crop
        float f0 = 0.f, f1 = 0.f, f2 = 0.f, f3 = 0.f;
        if (p < 75) {                    // off+299 <= 8999: always in bounds
            const float* gp = chan + offp[r] + p * 4;
            f0 = gp[0]; f1 = gp[1]; f2 = gp[2]; f3 = gp[3];
        }
        bf16x4 v;
        v[0] = (bf16)f0; v[1] = (bf16)f1; v[2] = (bf16)f2; v[3] = (bf16)f3;
        *(bf16x4*)(dst + r * ROWB + p * 8) = v;   // 8B-aligned ds_write_b64
    }
}

__global__ __launch_bounds__(1024, 4) void st_mfma(
        const float* __restrict__ input,    // [NCH, TT] fp32
        const int*   __restrict__ offsets,  // [NCH, KK] int32
        const bf16*  __restrict__ tab,      // W in B-frag order
        float*       __restrict__ out) {    // [NCH, KK, NB] fp32
    __shared__ __align__(16) unsigned char wlds[WBYTES];   // 61440 B W table
    __shared__ __align__(16) unsigned char cb[2][CBB];     // 2 x 41984 B crops
    __shared__ __align__(16) float part[KK][3];            // band partials

    const int bc   = blockIdx.x;       // 0..511
    const int tid  = threadIdx.x;
    const int wid  = tid >> 6;         // 0..15
    const int lane = tid & 63;
    const int ch0  = bc * CPB;

    // ---- prologue: async-stage W (60 x 1024 B chunks, 4 per wave) ----
    if (wid < 15) {
#pragma unroll
        for (int i = 0; i < 4; ++i) {
            int chunk = wid * 4 + i;   // 0..59
            __builtin_amdgcn_global_load_lds(
                (const __attribute__((address_space(1))) void*)((const unsigned char*)tab + chunk * 1024 + lane * 16),
                (__attribute__((address_space(3))) void*)(wlds + chunk * 1024),
                16, 0, 0);
        }
    }
    // ---- prologue: gather channel 0 with ALL 16 waves (5 chunks/thread) ----
    gather_ch(input + (size_t)ch0 * TT, offsets + (size_t)ch0 * KK,
              cb[0], tid, 1024, 5);

    // compute-wave constants
    const int m    = wid & 3;     // M-tile: crops m*16 .. m*16+15
    const int pg   = wid >> 2;    // bin group (pg<3): cos nt=pg, sin nt=pg+3
    const int quad = lane >> 4;
    const int c    = lane & 15;
    // W frags for this wave: contiguous 16B/lane -> conflict-free b128
    const unsigned char* wbase = wlds + pg * 1024 + lane * 16;
    // A row base: bank = 4*((c+quad) mod 8) -> 2 lanes per 4-bank group per
    // 16-lane phase = conflict-free b128
    const int arow = (m * 16 + c) * ROWB + quad * 16;

    for (int ch = 0; ch < CPB; ++ch) {
        __syncthreads();   // cb[ch&1] staged (drains vmcnt+lgkmcnt); part free

        if (wid < 12) {
            // ---- k-loop: pure LDS + MFMA, conflict-free ----
            const unsigned char* ab = cb[ch & 1] + arow;
            f32x4 acc_c = {0.f,0.f,0.f,0.f}, acc_s = {0.f,0.f,0.f,0.f};
#pragma unroll
            for (int ks = 0; ks < 10; ++ks) {
                bf16x8 a  = *(const bf16x8*)(ab + ks * 64);
                bf16x8 wc = *(const bf16x8*)(wbase + ks * 6144);
                bf16x8 wn = *(const bf16x8*)(wbase + ks * 6144 + 3072);
                acc_c = __builtin_amdgcn_mfma_f32_16x16x32_bf16(a, wc, acc_c, 0, 0, 0);
                acc_s = __builtin_amdgcn_mfma_f32_16x16x32_bf16(a, wn, acc_s, 0, 0, 0);
            }
            // power + in-quad band reduce; C/D: col = c (bin pg*16+c),
            // row = quad*4 + r (crop). Invalid bins (pg==2,c>2) are zero.
            float pv[4];
#pragma unroll
            for (int r = 0; r < 4; ++r) {
                float p = acc_c[r] * acc_c[r] + acc_s[r] * acc_s[r];
                pv[r] = p;
                float s = p;
#pragma unroll
                for (int d = 1; d < 16; d <<= 1) s += __shfl_xor(s, d, 64);
                if (c == 0) part[m * 16 + quad * 4 + r][pg] = s;
            }
            __syncthreads();   // part ready (gather writes also drained)

            float* ob = out + (size_t)(ch0 + ch) * NPAIR;
#pragma unroll
            for (int r = 0; r < 4; ++r) {
                int crop = m * 16 + quad * 4 + r;
                float s = part[crop][0] + part[crop][1] + part[crop][2];
                float rinv = __builtin_amdgcn_rcpf(s);
                if (pg < 2 || c < 3)
                    ob[crop * NB + pg * 16 + c] = pv[r] * rinv;
            }
        } else {
            // ---- producer waves: gather NEXT channel into the other buffer ----
            if (ch + 1 < CPB) {
                int chn = ch0 + ch + 1;
                gather_ch(input + (size_t)chn * TT, offsets + (size_t)chn * KK,
                          cb[(ch + 1) & 1], tid - 768, 256, 20);
            }
            __syncthreads();   // match compute waves' mid-channel barrier
        }
    }
}

extern "C" void kernel_launch(void* const* d_in, const int* in_sizes, int n_in,
                              void* d_out, int out_size, void* d_ws, size_t ws_size,
                              hipStream_t stream) {
    const float* input   = (const float*)d_in[0];  // [256,16,9000] fp32
    const int*   offsets = (const int*)d_in[1];    // [256,16,64] int32
    float*       out     = (float*)d_out;          // [256,16,64,35] fp32
    bf16*        tab     = (bf16*)d_ws;            // 61440 B

    // d_ws is re-poisoned before every timed launch -> rebuild table each call.
    build_w<<<(NFRAG_ELEMS + 255) / 256, 256, 0, stream>>>(tab);
    st_mfma<<<NBLK, 1024, 0, stream>>>(input, offsets, tab, out);
}

// Round 7
// 243.210 us; speedup vs baseline: 1.6712x; 1.6712x over previous
//
#include <hip/hip_runtime.h>
#include <math.h>

// Problem constants
#define TT 9000          // samples per channel
#define DT 300           // crop length
#define KK 64            // crops per channel
#define NB 35            // band bins: rfft bins 7..41
#define KMIN 7
#define NCH 4096         // B*C channels
#define NPAIR (KK * NB)  // 2240 outputs per channel

// GEMM per channel: C[64 x 96] = A[64 x 320] * W[320 x 96]  (16x16x32 bf16 MFMA)
// v7 (resubmit: previous round failed on container acquisition, not the kernel)
//    = v1's wave decomposition (wave = M-tile, reads A ONCE, all 6 nt: 2.7x
//      more wave-efficient than v5's pg-split by the cross-version record)
//    + v5's W-in-LDS (v1's only flaw was W streamed from global, latency-bound)
//    + v4's bf16 sig (18 KB) so W(60K)+sig(18K) = 79.7 KB -> 2 blocks/CU
//    + 8 channels per block so the W stage is amortized (512 blocks = 2/CU).
// v6 post-mortem: dedicated producer waves + 1 block/CU = fully exposed
// latency (253us). Here overlap comes from 2 co-resident blocks ping-ponging
// stage/compute, and the k-loop is pure {ds_read + MFMA}.
// Per channel per CU: A-build 120 b32-ish reads + 240 conflict-free W b128
// + 240 MFMA ~= 4.1k LDS cycles (vs v5's measured ~11k).

typedef __bf16 bf16;
typedef __attribute__((ext_vector_type(8))) __bf16 bf16x8;
typedef __attribute__((ext_vector_type(4))) __bf16 bf16x4;
typedef __attribute__((ext_vector_type(4))) float f32x4;

#define NFRAG_ELEMS (10 * 6 * 64 * 8)   // 30720 bf16 = 61440 B in d_ws
#define WBYTES 61440

// W table in B-fragment order: flat idx ((kstep*6 + nt)*64 + lane)*8 + j
// B-frag layout (16x16x32): lane l holds B[k = kstep*32 + (l>>4)*8 + j][n = l&15]
__global__ void build_w(bf16* __restrict__ tab) {
    int i = blockIdx.x * blockDim.x + threadIdx.x;
    if (i >= NFRAG_ELEMS) return;
    int j    = i & 7;
    int l    = (i >> 3) & 63;
    int f    = i >> 9;           // frag index = kstep*6 + nt
    int nt   = f % 6;
    int ks   = f / 6;
    int quad = l >> 4;
    int c    = l & 15;
    int k    = ks * 32 + quad * 8 + j;   // time index 0..319
    int jf   = (nt % 3) * 16 + c;        // band bin index 0..47
    float v = 0.0f;
    if (jf <= NB - 1 && k < DT) {
        int bin = jf + KMIN;                       // rfft bin 7..41
        int ph  = (bin * k) % DT;                  // exact integer phase
        float ang = 0.02094395102393195f * (float)ph;  // 2*pi/300 * ph
        v = (nt >= 3) ? sinf(ang) : cosf(ang);
    }
    tab[i] = (bf16)v;
}

#define SPAD 9024           // bf16 samples incl. zeroed tail (reads reach 9021)
#define CPB  8              // channels per block
#define NBLK (NCH / CPB)    // 512 blocks = 2 resident per CU

__global__ __launch_bounds__(256, 2) void st_mfma(
        const float* __restrict__ input,    // [NCH, TT] fp32
        const int*   __restrict__ offsets,  // [NCH, KK] int32
        const bf16*  __restrict__ tab,      // W in B-frag order
        float*       __restrict__ out) {    // [NCH, KK, NB] fp32
    __shared__ __align__(16) bf16 sig[SPAD];               // 18048 B channel
    __shared__ __align__(16) unsigned char wlds[WBYTES];   // 61440 B W table
    __shared__ int offs[KK];                               // 256 B
    // total 79744 -> 79872 (256B granule): exactly 2 blocks/CU

    const int tid  = threadIdx.x;
    const int w    = tid >> 6;    // wave = M-tile (16 crops)
    const int lane = tid & 63;
    const int quad = lane >> 4;
    const int c    = lane & 15;

    // ---- stage W ONCE per block (amortized over 8 channels) ----
    // 60 chunks x 1024 B, 15 per wave; linear both sides -> global_load_lds.
    // Completion is drained by the first channel's __syncthreads().
#pragma unroll
    for (int i = 0; i < 15; ++i) {
        int chunk = w * 15 + i;
        __builtin_amdgcn_global_load_lds(
            (const __attribute__((address_space(1))) void*)((const unsigned char*)tab + chunk * 1024 + lane * 16),
            (__attribute__((address_space(3))) void*)(wlds + chunk * 1024),
            16, 0, 0);
    }

#pragma unroll 1
    for (int ch = 0; ch < CPB; ++ch) {
        const int chg = blockIdx.x * CPB + ch;

        // ---- stage channel -> bf16 LDS (coalesced float4 reads, b64 writes) ----
        const float4* src = (const float4*)(input + (size_t)chg * TT);
#pragma unroll
        for (int i = 0; i < 9; ++i) {        // 9*256 = 2304 >= 2250 chunks
            int idx = tid + i * 256;
            if (idx < TT / 4) {
                float4 v = src[idx];
                bf16x4 b;
                b[0] = (bf16)v.x; b[1] = (bf16)v.y; b[2] = (bf16)v.z; b[3] = (bf16)v.w;
                *(bf16x4*)(sig + idx * 4) = b;   // byte 8*idx: 8B-aligned
            }
        }
        if (tid < SPAD - TT) sig[TT + tid] = (bf16)0.0f;  // zero pad
        if (tid < KK) offs[tid] = offsets[(size_t)chg * KK + tid];
        __syncthreads();   // sig/offs visible; (iter 0: also drains W vmcnt)

        // A-frag: lane holds A[m = c][k = ks*32 + quad*8 + j], j=0..7.
        // s = off + ks*32 + quad*8; parity(s) == parity(off) -> one per-lane
        // alignbit shift for the whole channel (branchless realign).
        const int off = offs[w * 16 + c];
        const int d0  = (off + quad * 8) >> 1;          // dword index (floor)
        const unsigned sh = (unsigned)((off & 1) << 4); // 0 or 16
        const int* ip = (const int*)sig;

        f32x4 acc[6];
#pragma unroll
        for (int nt = 0; nt < 6; ++nt) acc[nt] = (f32x4){0.f, 0.f, 0.f, 0.f};

#pragma unroll
        for (int ks = 0; ks < 10; ++ks) {
            // A fragment: 5 dword LDS reads (ds_read2_b32 pairs) + 4 alignbit
            const int db = d0 + ks * 16;
            int dw0 = ip[db + 0], dw1 = ip[db + 1], dw2 = ip[db + 2],
                dw3 = ip[db + 3], dw4 = ip[db + 4];
            union { unsigned u[4]; bf16x8 v; } a;
            a.u[0] = __builtin_amdgcn_alignbit((unsigned)dw1, (unsigned)dw0, sh);
            a.u[1] = __builtin_amdgcn_alignbit((unsigned)dw2, (unsigned)dw1, sh);
            a.u[2] = __builtin_amdgcn_alignbit((unsigned)dw3, (unsigned)dw2, sh);
            a.u[3] = __builtin_amdgcn_alignbit((unsigned)dw4, (unsigned)dw3, sh);

            // 6 conflict-free W b128 reads + 6 independent MFMAs
#pragma unroll
            for (int nt = 0; nt < 6; ++nt) {
                bf16x8 wf = *(const bf16x8*)(wlds + ks * 6144 + nt * 1024 + lane * 16);
                acc[nt] = __builtin_amdgcn_mfma_f32_16x16x32_bf16(a.v, wf, acc[nt], 0, 0, 0);
            }
        }

        // ---- epilogue, all in registers (v1-proven) ----
        // C/D: col = lane&15, row = quad*4 + r. cos_j in acc[i], sin_j in
        // acc[i+3] (same lane), j = i*16 + c. Band sum is in-quad (16 lanes).
        float* o = out + (size_t)chg * NPAIR;
#pragma unroll
        for (int r = 0; r < 4; ++r) {
            float p0 = acc[0][r] * acc[0][r] + acc[3][r] * acc[3][r];  // j = c
            float p1 = acc[1][r] * acc[1][r] + acc[4][r] * acc[4][r];  // j = 16+c
            float p2 = acc[2][r] * acc[2][r] + acc[5][r] * acc[5][r];  // j = 32+c (c<=2)
            float s = p0 + p1 + ((c <= 2) ? p2 : 0.0f);
#pragma unroll
            for (int d = 1; d < 16; d <<= 1) s += __shfl_xor(s, d, 64);  // in-quad
            float rinv = 1.0f / s;
            int crop = w * 16 + quad * 4 + r;
            float* oc = o + crop * NB;
            oc[c] = p0 * rinv;
            oc[16 + c] = p1 * rinv;
            if (c <= 2) oc[32 + c] = p2 * rinv;
        }
        __syncthreads();   // all sig reads done before next channel's stage
    }
}

extern "C" void kernel_launch(void* const* d_in, const int* in_sizes, int n_in,
                              void* d_out, int out_size, void* d_ws, size_t ws_size,
                              hipStream_t stream) {
    const float* input   = (const float*)d_in[0];  // [256,16,9000] fp32
    const int*   offsets = (const int*)d_in[1];    // [256,16,64] int32
    float*       out     = (float*)d_out;          // [256,16,64,35] fp32
    bf16*        tab     = (bf16*)d_ws;            // 61440 B

    // d_ws is re-poisoned before every timed launch -> rebuild table each call.
    build_w<<<(NFRAG_ELEMS + 255) / 256, 256, 0, stream>>>(tab);
    st_mfma<<<NBLK, 256, 0, stream>>>(input, offsets, tab, out);
}

// Round 9
// 225.445 us; speedup vs baseline: 1.8029x; 1.0788x over previous
//
#include <hip/hip_runtime.h>
#include <math.h>

// Problem constants
#define TT 9000          // samples per channel
#define DT 300           // crop length
#define KK 64            // crops per channel
#define NB 35            // band bins: rfft bins 7..41
#define KMIN 7
#define NCH 4096         // B*C channels
#define NPAIR (KK * NB)  // 2240 outputs per channel

// GEMM per channel: C[64 x 96] = A[64 x 320] * W[320 x 96]  (16x16x32 bf16 MFMA)
// v8 (resubmit: R8 failed on container acquisition, not the kernel)
//    = v7's per-wave loop (best per-wave efficiency: dur*occ 18 vs v1's 35)
//      at 4x the residency, with staging overlapped:
//  - 256 blocks x 1024 threads, 1 block/CU; 16 channels per block in 4
//    iterations of 4 channels
//  - LDS: W 60 KB + sig[4] 72 KB (bf16) + offs 1 KB = 131.5 KB -> 16 waves/CU
//    (50% cap, 4 waves/SIMD: v1-level latency hiding, v7-level loop)
//  - wave (chl=wid>>2, m=wid&3): v7 k-loop {3 A-dword reads + 4 alignbit +
//    6 conflict-free W b128 + 6 MFMA} per ks, register epilogue
//  - T14 staging: each 256-group owns a channel; next iteration's 9 float4
//    per thread load into REGISTERS during compute, ds_write after the read
//    barrier -> the ~23 us aggregate HBM stream drains under compute.
// v7 accounting: LDS floor ~32us, MFMA 8us, HBM 23us; measured 87 => ~55us
// exposed latency at 8 waves/CU. This attacks exactly that term.

typedef __bf16 bf16;
typedef __attribute__((ext_vector_type(8))) __bf16 bf16x8;
typedef __attribute__((ext_vector_type(4))) __bf16 bf16x4;
typedef __attribute__((ext_vector_type(4))) float f32x4;

#define NFRAG_ELEMS (10 * 6 * 64 * 8)   // 30720 bf16 = 61440 B in d_ws
#define WBYTES 61440

// W table in B-fragment order: flat idx ((kstep*6 + nt)*64 + lane)*8 + j
// B-frag layout (16x16x32): lane l holds B[k = kstep*32 + (l>>4)*8 + j][n = l&15]
__global__ void build_w(bf16* __restrict__ tab) {
    int i = blockIdx.x * blockDim.x + threadIdx.x;
    if (i >= NFRAG_ELEMS) return;
    int j    = i & 7;
    int l    = (i >> 3) & 63;
    int f    = i >> 9;           // frag index = kstep*6 + nt
    int nt   = f % 6;
    int ks   = f / 6;
    int quad = l >> 4;
    int c    = l & 15;
    int k    = ks * 32 + quad * 8 + j;   // time index 0..319
    int jf   = (nt % 3) * 16 + c;        // band bin index 0..47
    float v = 0.0f;
    if (jf <= NB - 1 && k < DT) {
        int bin = jf + KMIN;                       // rfft bin 7..41
        int ph  = (bin * k) % DT;                  // exact integer phase
        float ang = 0.02094395102393195f * (float)ph;  // 2*pi/300 * ph
        v = (nt >= 3) ? sinf(ang) : cosf(ang);
    }
    tab[i] = (bf16)v;
}

#define SPAD 9024           // bf16 samples incl. zeroed tail (reads reach 9021)
#define CHPI 4              // channels per iteration (one per 256-thread group)
#define NIT  4              // iterations per block
#define CPB  (CHPI * NIT)   // 16 channels per block
#define NBLK (NCH / CPB)    // 256 blocks = 1 per CU

__global__ __launch_bounds__(1024, 1) void st_mfma(
        const float* __restrict__ input,    // [NCH, TT] fp32
        const int*   __restrict__ offsets,  // [NCH, KK] int32
        const bf16*  __restrict__ tab,      // W in B-frag order
        float*       __restrict__ out) {    // [NCH, KK, NB] fp32
    __shared__ __align__(16) bf16 sig[CHPI][SPAD];         // 72192 B
    __shared__ __align__(16) unsigned char wlds[WBYTES];   // 61440 B
    __shared__ int offs[CHPI * KK];                        // 1024 B

    const int tid  = threadIdx.x;
    const int wid  = tid >> 6;    // 0..15
    const int lane = tid & 63;
    const int cg   = tid >> 8;    // staging: channel-group 0..3
    const int st   = tid & 255;   // staging tid within group
    const int ch0  = blockIdx.x * CPB;

    // ---- stage W once per block: 60 x 1024 B chunks, 4 per wave (15 waves) ----
    if (wid < 15) {
#pragma unroll
        for (int i = 0; i < 4; ++i) {
            int chunk = wid * 4 + i;
            __builtin_amdgcn_global_load_lds(
                (const __attribute__((address_space(1))) void*)((const unsigned char*)tab + chunk * 1024 + lane * 16),
                (__attribute__((address_space(3))) void*)(wlds + chunk * 1024),
                16, 0, 0);
        }
    }
    // zero tail pad once (never overwritten: stage writes only samples <9000)
    if (st < SPAD - TT) sig[cg][TT + st] = (bf16)0.0f;

    // ---- prologue: stage iteration 0 (load -> cvt -> write) ----
    float4 rb[9];
    int roff = 0;
    {
        const float4* src = (const float4*)(input + (size_t)(ch0 + cg) * TT);
#pragma unroll
        for (int i = 0; i < 9; ++i) {
            int idx = st + i * 256;
            if (idx < TT / 4) rb[i] = src[idx];
        }
        if (tid < CHPI * KK) roff = offsets[(size_t)ch0 * KK + tid];
    }
#pragma unroll
    for (int i = 0; i < 9; ++i) {
        int idx = st + i * 256;
        if (idx < TT / 4) {
            bf16x4 b;
            b[0] = (bf16)rb[i].x; b[1] = (bf16)rb[i].y;
            b[2] = (bf16)rb[i].z; b[3] = (bf16)rb[i].w;
            *(bf16x4*)(&sig[cg][idx * 4]) = b;
        }
    }
    if (tid < CHPI * KK) offs[tid] = roff;
    __syncthreads();   // sig[0..3], offs visible; drains W-stage vmcnt too

    const int chl  = wid >> 2;   // channel within iteration (0..3)
    const int m    = wid & 3;    // M-tile (16 crops)
    const int quad = lane >> 4;
    const int c    = lane & 15;

#pragma unroll 1
    for (int it = 0; it < NIT; ++it) {
        // ---- T14 issue-early: next iteration's channel into registers ----
        if (it + 1 < NIT) {
            const float4* src = (const float4*)(input + (size_t)(ch0 + (it + 1) * CHPI + cg) * TT);
#pragma unroll
            for (int i = 0; i < 9; ++i) {
                int idx = st + i * 256;
                if (idx < TT / 4) rb[i] = src[idx];
            }
            if (tid < CHPI * KK)
                roff = offsets[(size_t)(ch0 + (it + 1) * CHPI) * KK + tid];
        }

        // ---- compute this wave's channel (v7-proven loop) ----
        const int chg = ch0 + it * CHPI + chl;
        const int off = offs[chl * KK + m * 16 + c];
        const int d0  = (off + quad * 8) >> 1;          // dword index (floor)
        const unsigned sh = (unsigned)((off & 1) << 4); // 0 or 16
        const int* ip = (const int*)&sig[chl][0];

        f32x4 acc[6];
#pragma unroll
        for (int nt = 0; nt < 6; ++nt) acc[nt] = (f32x4){0.f, 0.f, 0.f, 0.f};

#pragma unroll
        for (int ks = 0; ks < 10; ++ks) {
            const int db = d0 + ks * 16;
            int dw0 = ip[db + 0], dw1 = ip[db + 1], dw2 = ip[db + 2],
                dw3 = ip[db + 3], dw4 = ip[db + 4];
            union { unsigned u[4]; bf16x8 v; } a;
            a.u[0] = __builtin_amdgcn_alignbit((unsigned)dw1, (unsigned)dw0, sh);
            a.u[1] = __builtin_amdgcn_alignbit((unsigned)dw2, (unsigned)dw1, sh);
            a.u[2] = __builtin_amdgcn_alignbit((unsigned)dw3, (unsigned)dw2, sh);
            a.u[3] = __builtin_amdgcn_alignbit((unsigned)dw4, (unsigned)dw3, sh);
#pragma unroll
            for (int nt = 0; nt < 6; ++nt) {
                bf16x8 wf = *(const bf16x8*)(wlds + ks * 6144 + nt * 1024 + lane * 16);
                acc[nt] = __builtin_amdgcn_mfma_f32_16x16x32_bf16(a.v, wf, acc[nt], 0, 0, 0);
            }
        }

        // ---- register epilogue (v1/v7-proven) ----
        // C/D: col = lane&15, row = quad*4 + r; cos_j acc[i], sin_j acc[i+3].
        float* o = out + (size_t)chg * NPAIR;
#pragma unroll
        for (int r = 0; r < 4; ++r) {
            float p0 = acc[0][r] * acc[0][r] + acc[3][r] * acc[3][r];  // j = c
            float p1 = acc[1][r] * acc[1][r] + acc[4][r] * acc[4][r];  // j = 16+c
            float p2 = acc[2][r] * acc[2][r] + acc[5][r] * acc[5][r];  // j = 32+c
            float s = p0 + p1 + ((c <= 2) ? p2 : 0.0f);
#pragma unroll
            for (int d = 1; d < 16; d <<= 1) s += __shfl_xor(s, d, 64);  // in-quad
            float rinv = 1.0f / s;
            int crop = m * 16 + quad * 4 + r;
            float* oc = o + crop * NB;
            oc[c] = p0 * rinv;
            oc[16 + c] = p1 * rinv;
            if (c <= 2) oc[32 + c] = p2 * rinv;
        }

        __syncthreads();   // all sig/offs reads of this iteration done

        // ---- T14 write-late: commit next iteration's staging ----
        if (it + 1 < NIT) {
#pragma unroll
            for (int i = 0; i < 9; ++i) {
                int idx = st + i * 256;
                if (idx < TT / 4) {
                    bf16x4 b;
                    b[0] = (bf16)rb[i].x; b[1] = (bf16)rb[i].y;
                    b[2] = (bf16)rb[i].z; b[3] = (bf16)rb[i].w;
                    *(bf16x4*)(&sig[cg][idx * 4]) = b;
                }
            }
            if (tid < CHPI * KK) offs[tid] = roff;
            __syncthreads();   // staged data visible for next iteration
        }
    }
}

extern "C" void kernel_launch(void* const* d_in, const int* in_sizes, int n_in,
                              void* d_out, int out_size, void* d_ws, size_t ws_size,
                              hipStream_t stream) {
    const float* input   = (const float*)d_in[0];  // [256,16,9000] fp32
    const int*   offsets = (const int*)d_in[1];    // [256,16,64] int32
    float*       out     = (float*)d_out;          // [256,16,64,35] fp32
    bf16*        tab     = (bf16*)d_ws;            // 61440 B

    // d_ws is re-poisoned before every timed launch -> rebuild table each call.
    build_w<<<(NFRAG_ELEMS + 255) / 256, 256, 0, stream>>>(tab);
    st_mfma<<<NBLK, 1024, 0, stream>>>(input, offsets, tab, out);
}